// Round 15
// baseline (326.871 us; speedup 1.0000x reference)
//
#include <hip/hip_runtime.h>
#include <hip/hip_bf16.h>
#include <cstdio>

// Problem constants (B=2, T=2048, D=1024, H=4096, O=1024, E=8, top-k=2)
#define NT_TOK 4096
#define D_DIM  1024
#define H_DIM  4096
#define O_DIM  1024
#define E_NUM  8
#define PAIRS  8192      // NT_TOK * 2
#define WI_SLOTS 72      // max m-tiles at BM=128: 64 + 7 rounding < 72
#define WI64_SLOTS 136   // max m-tiles at BM=64: 128 + 7 rounding < 136; 8*136 % 8 == 0
#define BK 64
#define G1_BLOCKS (32 * WI_SLOTS)     // 2304 gemm1 blocks
#define G2_BLOCKS (8 * WI64_SLOTS)    // 1088 gemm2 blocks; % 8 == 0
#define TW1_BLOCKS (E_NUM * 1024)     // 8192 W1-transpose tiles
#define TW2_BLOCKS (E_NUM * 1024)     // 8192 W2-transpose tiles

typedef short bf16x8 __attribute__((ext_vector_type(8)));
typedef float f32x4  __attribute__((ext_vector_type(4)));

// round-to-nearest-even fp32 -> bf16 bits
__device__ __forceinline__ unsigned short bfr(float f){
  unsigned u = __float_as_uint(f);
  unsigned r = (u + 0x7FFFu + ((u >> 16) & 1u)) >> 16;
  return (unsigned short)r;
}

// async global->LDS, 16B per lane; lds dest is wave-uniform base (HW adds lane*16)
__device__ __forceinline__ void gload_lds16(const void* g, void* l){
  __builtin_amdgcn_global_load_lds((const __attribute__((address_space(1))) unsigned int*)g,
                                   (__attribute__((address_space(3))) unsigned int*)l,
                                   16, 0, 0);
}

// ---------------- 64x64 cast+transpose tile body ([R][C] f32 -> [C][R] bf16)
__device__ __forceinline__ void transpose_tile(const float* __restrict__ in,
                                               unsigned short* __restrict__ out,
                                               int R, int C, int bx, int by, int bz,
                                               char* smem){
  float (*t)[65] = (float(*)[65])smem;
  long long base = (long long)bz * R * C;
  int c0 = bx * 64, r0 = by * 64;
  int tid = threadIdx.x;
  int rr = tid >> 4;           // 0..15
  int cc = (tid & 15) * 4;     // 0,4,...,60
  #pragma unroll
  for (int i = 0; i < 4; i++){
    int r = rr + i * 16;
    float4 v = *(const float4*)&in[base + (long long)(r0 + r) * C + c0 + cc];
    t[r][cc] = v.x; t[r][cc+1] = v.y; t[r][cc+2] = v.z; t[r][cc+3] = v.w;
  }
  __syncthreads();
  #pragma unroll
  for (int i = 0; i < 4; i++){
    int oc = rr + i * 16;      // output row (= input col)
    unsigned int lo = (unsigned int)bfr(t[cc][oc])   | ((unsigned int)bfr(t[cc+1][oc]) << 16);
    unsigned int hi = (unsigned int)bfr(t[cc+2][oc]) | ((unsigned int)bfr(t[cc+3][oc]) << 16);
    *(uint2*)&out[base + (long long)(c0 + oc) * R + r0 + cc] = make_uint2(lo, hi);
  }
}

// ================== K1: gating (top-2) + fused hist + x->bf16 cast  ∥  W1 transpose
__global__ __launch_bounds__(256) void gate_w1t_kernel(const float* __restrict__ x,
                                                       const float* __restrict__ Wg,
                                                       const float* __restrict__ bg,
                                                       const float* __restrict__ W1,
                                                       unsigned short* __restrict__ xb,
                                                       unsigned short* __restrict__ W1t,
                                                       int*   __restrict__ pe,
                                                       float* __restrict__ pw,
                                                       int*   __restrict__ chist){
  __shared__ __align__(16) char smem[16640];
  int bid = blockIdx.x;
  if (bid >= NT_TOK/4){
    // W1 [D][H] -> W1t [H][D] per expert; bx over H/64 (64), by over D/64 (16)
    int tb = bid - NT_TOK/4;
    int e = tb >> 10, t = tb & 1023;
    transpose_tile(W1, W1t, D_DIM, H_DIM, t & 63, t >> 6, e, smem);
    return;
  }
  int wid = threadIdx.x >> 6, lane = threadIdx.x & 63;
  int t = bid * 4 + wid;
  const float* xr = x + (long long)t * D_DIM;
  unsigned short* xo = xb + (long long)t * D_DIM;
  float acc[E_NUM];
  #pragma unroll
  for (int e = 0; e < E_NUM; e++) acc[e] = 0.f;
  for (int d = lane; d < D_DIM; d += 64){
    float xv = xr[d];
    xo[d] = bfr(xv);                          // fused bf16 cast
    const float* wr = Wg + d * E_NUM;
    #pragma unroll
    for (int e = 0; e < E_NUM; e++) acc[e] += xv * wr[e];
  }
  #pragma unroll
  for (int off = 32; off; off >>= 1)
    #pragma unroll
    for (int e = 0; e < E_NUM; e++) acc[e] += __shfl_xor(acc[e], off);
  if (lane == 0){
    float l[E_NUM];
    float m = -1e30f;
    #pragma unroll
    for (int e = 0; e < E_NUM; e++){ l[e] = acc[e] + bg[e]; m = fmaxf(m, l[e]); }
    float ex[E_NUM];
    #pragma unroll
    for (int e = 0; e < E_NUM; e++) ex[e] = expf(l[e] - m);
    int e0 = 0;
    #pragma unroll
    for (int e = 1; e < E_NUM; e++) if (ex[e] > ex[e0]) e0 = e;      // first max
    int e1 = -1;
    for (int e = 0; e < E_NUM; e++){ if (e == e0) continue; if (e1 < 0 || ex[e] > ex[e1]) e1 = e; }
    float s = ex[e0] + ex[e1];
    pe[2*t]   = e0;  pw[2*t]   = ex[e0] / s;
    pe[2*t+1] = e1;  pw[2*t+1] = ex[e1] / s;
    int chunk = (2*t) >> 8;                   // both pair slots of t are in the same 256-chunk
    atomicAdd(&chist[chunk * E_NUM + e0], 1);
    atomicAdd(&chist[chunk * E_NUM + e1], 1);
  }
}

// ---------- scan + deterministic scatter + work-item tables (128-row and 64-row)
__global__ __launch_bounds__(256) void scatter_kernel(const int* __restrict__ pe,
                                                      const int* __restrict__ chunk_hist,
                                                      int* __restrict__ cnt,
                                                      int* __restrict__ offs,
                                                      int* __restrict__ row_pair,
                                                      int* __restrict__ wi,
                                                      int* __restrict__ wi64){
  __shared__ int hist[32][E_NUM];
  __shared__ int pref[32][E_NUM];
  __shared__ int total[E_NUM];
  __shared__ int off_s[E_NUM + 1];
  __shared__ unsigned char ex[PAIRS];
  int tid = threadIdx.x;
  for (int i = tid; i < PAIRS; i += 256) ex[i] = (unsigned char)pe[i];
  { int c = tid >> 3, e = tid & 7; hist[c][e] = chunk_hist[tid]; }
  __syncthreads();
  if (tid < E_NUM){
    int s = 0;
    for (int c = 0; c < 32; c++){ pref[c][tid] = s; s += hist[c][tid]; }
    total[tid] = s;
  }
  __syncthreads();
  if (tid == 0){
    int s = 0;
    for (int e = 0; e < E_NUM; e++){ off_s[e] = s; s += total[e]; }
    off_s[E_NUM] = s;
    int idx = 0, idx2 = 0;
    for (int e = 0; e < E_NUM; e++){
      int mts = (total[e] + 127) >> 7;
      for (int m = 0; m < mts; m++) wi[idx++] = (e << 8) | m;
      int m64 = (total[e] + 63) >> 6;
      for (int m = 0; m < m64; m++) wi64[idx2++] = (e << 8) | m;
    }
    for (; idx < WI_SLOTS; idx++) wi[idx] = -1;
    for (; idx2 < WI64_SLOTS; idx2++) wi64[idx2] = -1;
  }
  __syncthreads();
  if (tid < E_NUM){ cnt[tid] = total[tid]; offs[tid] = off_s[tid]; }
  int c = tid >> 3, e = tid & 7;
  int base = off_s[e] + pref[c][e];
  int local = 0;
  for (int i = 0; i < 256; i++){
    int p = c * 256 + i;
    if (ex[p] == (unsigned char)e){
      row_pair[base + local] = p;
      local++;
    }
  }
}

// ================== K3: grouped GEMM1 (m97 structure, NATURAL order)  ∥  W2 transpose
// hidden[pos][h] = relu( x[token(pos)] . W1[e][:, h] + b1[e][h] ), bf16 out
// Staged coalesced epilogue (R14: gemm1 dispatch dropped 137 -> <130 us).
__global__ __launch_bounds__(256, 3) void gemm1_w2t_kernel(const unsigned short* __restrict__ xb,
                                                           const unsigned short* __restrict__ W1t,
                                                           const float* __restrict__ W2,
                                                           unsigned short* __restrict__ W2t,
                                                           const float* __restrict__ b1,
                                                           const int* __restrict__ row_pair,
                                                           const int* __restrict__ cnt,
                                                           const int* __restrict__ offs,
                                                           const int* __restrict__ wi,
                                                           unsigned short* __restrict__ hidden){
  __shared__ __align__(16) char smem[34816];   // max(As+Bs 32KB, Hs 128x136x2B, transpose 16.6KB)
  int bid = blockIdx.x;
  if (bid >= G1_BLOCKS){
    // W2 [H][O] -> W2t [O][H] per expert; bx over O/64 (16), by over H/64 (64)
    int tb = bid - G1_BLOCKS;
    int e = tb >> 10, t = tb & 1023;
    transpose_tile(W2, W2t, H_DIM, O_DIM, t & 15, t >> 4, e, smem);
    return;
  }
  int nt = bid & 31, slot = bid >> 5;
  int w = wi[slot];
  if (w < 0) return;
  int e = w >> 8, mt = w & 255;
  int count = cnt[e];
  int m0 = mt * 128;
  int seg = offs[e];
  int valid = count - m0;
  int n0 = nt * 128;

  unsigned short* As = (unsigned short*)smem;            // 16 KB
  unsigned short* Bs = (unsigned short*)(smem + 16384);  // 16 KB

  int tid = threadIdx.x;
  int wv = tid >> 6, lane = tid & 63;
  int wr = wv >> 1, wc = wv & 1;              // wave tile: rows wr*64..+63, cols wc*64..+63
  int lo = lane & 15, hi = lane >> 4;
  int l3 = lane >> 3;                         // 0..7 (= staged row & 7)
  int srcel = ((lane & 7) ^ l3) << 3;         // inverse-swizzled source column (elements)

  const unsigned short* w1e = W1t + (long long)e * H_DIM * D_DIM;   // [H][D]

  const unsigned short* pa[4];
  const unsigned short* pb[4];
  #pragma unroll
  for (int h = 0; h < 4; h++){
    int r = h * 32 + wv * 8 + l3;
    int pos = seg + m0 + r; if (pos > PAIRS - 1) pos = PAIRS - 1;
    int token = row_pair[pos] >> 1;
    pa[h] = xb + (long long)token * D_DIM + srcel;
    pb[h] = w1e + (long long)(n0 + r) * D_DIM + srcel;
  }

  f32x4 acc[4][4] = {};
  for (int kt = 0; kt < D_DIM / BK; ++kt){
    #pragma unroll
    for (int h = 0; h < 4; h++){
      gload_lds16(pa[h], &As[(h*32 + wv*8) * BK]);  pa[h] += BK;
      gload_lds16(pb[h], &Bs[(h*32 + wv*8) * BK]);  pb[h] += BK;
    }
    __syncthreads();
    bf16x8 aq[4][2], bq[4][2];
    #pragma unroll
    for (int n = 0; n < 4; n++)
      #pragma unroll
      for (int ks = 0; ks < 2; ks++){
        int br = wc*64 + n*16 + lo;
        bq[n][ks] = *(const bf16x8*)&Bs[br*BK + ((ks*32 + hi*8) ^ ((br & 7) << 3))];
      }
    #pragma unroll
    for (int m = 0; m < 4; m++)
      #pragma unroll
      for (int ks = 0; ks < 2; ks++){
        int ar = wr*64 + m*16 + lo;
        aq[m][ks] = *(const bf16x8*)&As[ar*BK + ((ks*32 + hi*8) ^ ((ar & 7) << 3))];
      }
    #pragma unroll
    for (int m = 0; m < 4; m++)
      #pragma unroll
      for (int n = 0; n < 4; n++)
        #pragma unroll
        for (int ks = 0; ks < 2; ks++)
          acc[m][n] = __builtin_amdgcn_mfma_f32_16x16x32_bf16(aq[m][ks], bq[n][ks], acc[m][n], 0, 0, 0);
    __syncthreads();
  }

  // ---- staged epilogue: acc -> LDS [128][136] (pad: <=2 lanes/bank) -> dwordx4 stores
  unsigned short* Hs = (unsigned short*)smem;
  const float* b1e = b1 + (long long)e * H_DIM;
  #pragma unroll
  for (int n = 0; n < 4; n++){
    int colL = wc*64 + n*16 + lo;
    float bias = b1e[n0 + colL];
    #pragma unroll
    for (int m = 0; m < 4; m++)
      #pragma unroll
      for (int j = 0; j < 4; j++){
        int rl = wr*64 + m*16 + hi*4 + j;
        float v = acc[m][n][j] + bias;
        v = v > 0.f ? v : 0.f;
        Hs[rl * 136 + colL] = bfr(v);
      }
  }
  __syncthreads();
  int row = tid >> 1, half = tid & 1;         // 2 threads/row, 128B each (fully packed sectors)
  if (row < valid){
    uint4* dst = (uint4*)&hidden[(long long)(seg + m0 + row) * H_DIM + n0 + half * 64];
    const uint4* src = (const uint4*)&Hs[row * 136 + half * 64];
    #pragma unroll
    for (int k = 0; k < 8; k++) dst[k] = src[k];
  }
}

// ============================================================== grouped GEMM2
// 64x128 tile (BM=64): 1088 blocks -> ~4.25/CU at (256,4); combined vgpr+agpr
// ~100 < 128 cap (R10 lesson: cap is vgpr+agpr). XCD-chunked (measured win).
// y[p][o] = hidden[pos] . W2[e][:,o] + b2[e][o]
__global__ __launch_bounds__(256, 4) void gemm2_kernel(const unsigned short* __restrict__ hidden,
                                                       const unsigned short* __restrict__ W2t,
                                                       const float* __restrict__ b2,
                                                       const int* __restrict__ row_pair,
                                                       const int* __restrict__ cnt,
                                                       const int* __restrict__ offs,
                                                       const int* __restrict__ wi64,
                                                       float* __restrict__ y){
  int bid = blockIdx.x;
  int fp = (bid & 7) * (G2_BLOCKS / 8) + (bid >> 3);
  int nt = fp & 7, slot = fp >> 3;
  int w = wi64[slot];
  if (w < 0) return;
  int e = w >> 8, mt = w & 255;
  int count = cnt[e];
  int m0 = mt * 64;
  int seg = offs[e];
  int valid = count - m0;
  int n0 = nt * 128;

  __shared__ unsigned short As[64 * BK];     // 8 KB
  __shared__ unsigned short Bs[128 * BK];    // 16 KB

  int tid = threadIdx.x;
  int wv = tid >> 6, lane = tid & 63;
  int wr = wv >> 1, wc = wv & 1;             // wave tile: rows wr*32..+31, cols wc*64..+63
  int lo = lane & 15, hi = lane >> 4;
  int l3 = lane >> 3;
  int srcel = ((lane & 7) ^ l3) << 3;

  const unsigned short* w2e = W2t + (long long)e * O_DIM * H_DIM;   // [O][H]

  const unsigned short* pa[2];
  const unsigned short* pb[4];
  #pragma unroll
  for (int g = 0; g < 2; g++){
    int r = wv * 16 + g * 8 + l3;            // rows 0..63
    long long pos = seg + m0 + r; if (pos > PAIRS - 1) pos = PAIRS - 1;
    pa[g] = hidden + pos * H_DIM + srcel;
  }
  #pragma unroll
  for (int h = 0; h < 4; h++){
    int r = h * 32 + wv * 8 + l3;            // rows 0..127
    pb[h] = w2e + (long long)(n0 + r) * H_DIM + srcel;
  }

  f32x4 acc[2][4] = {};
  for (int kt = 0; kt < H_DIM / BK; ++kt){
    #pragma unroll
    for (int g = 0; g < 2; g++){
      gload_lds16(pa[g], &As[(wv*16 + g*8) * BK]);  pa[g] += BK;
    }
    #pragma unroll
    for (int h = 0; h < 4; h++){
      gload_lds16(pb[h], &Bs[(h*32 + wv*8) * BK]);  pb[h] += BK;
    }
    __syncthreads();
    bf16x8 aq[2][2], bq[4][2];
    #pragma unroll
    for (int n = 0; n < 4; n++)
      #pragma unroll
      for (int ks = 0; ks < 2; ks++){
        int br = wc*64 + n*16 + lo;
        bq[n][ks] = *(const bf16x8*)&Bs[br*BK + ((ks*32 + hi*8) ^ ((br & 7) << 3))];
      }
    #pragma unroll
    for (int m = 0; m < 2; m++)
      #pragma unroll
      for (int ks = 0; ks < 2; ks++){
        int ar = wr*32 + m*16 + lo;
        aq[m][ks] = *(const bf16x8*)&As[ar*BK + ((ks*32 + hi*8) ^ ((ar & 7) << 3))];
      }
    #pragma unroll
    for (int m = 0; m < 2; m++)
      #pragma unroll
      for (int n = 0; n < 4; n++)
        #pragma unroll
        for (int ks = 0; ks < 2; ks++)
          acc[m][n] = __builtin_amdgcn_mfma_f32_16x16x32_bf16(aq[m][ks], bq[n][ks], acc[m][n], 0, 0, 0);
    __syncthreads();
  }

  const float* b2e = b2 + (long long)e * O_DIM;
  #pragma unroll
  for (int m = 0; m < 2; m++)
    #pragma unroll
    for (int j = 0; j < 4; j++){
      int rl = wr*32 + m*16 + hi*4 + j;
      if (rl < valid){
        int p = row_pair[seg + m0 + rl];
        float* yr = y + (long long)p * O_DIM;
        #pragma unroll
        for (int n = 0; n < 4; n++){
          int col = n0 + wc*64 + n*16 + lo;
          yr[col] = acc[m][n][j] + b2e[col];
        }
      }
    }
}

// ---------------------------------------------------------------- combine
__global__ __launch_bounds__(256) void combine_kernel(const float* __restrict__ y,
                                                      const int* __restrict__ pe,
                                                      const float* __restrict__ pw,
                                                      float* __restrict__ out){
  int t = blockIdx.x, tid = threadIdx.x;      // 256 threads * float4 = 1024 = O_DIM
  float w0 = pw[2*t], w1 = pw[2*t+1];
  float4 a = ((const float4*)(y + (long long)(2*t) * O_DIM))[tid];
  float4 b = ((const float4*)(y + (long long)(2*t+1) * O_DIM))[tid];
  float4 r;
  r.x = w0 * a.x + w1 * b.x;
  r.y = w0 * a.y + w1 * b.y;
  r.z = w0 * a.z + w1 * b.z;
  r.w = w0 * a.w + w1 * b.w;
  ((float4*)(out + (long long)t * O_DIM))[tid] = r;
}

// ---------------------------------------------------------------- host
extern "C" void kernel_launch(void* const* d_in, const int* in_sizes, int n_in,
                              void* d_out, int out_size, void* d_ws, size_t ws_size,
                              hipStream_t stream){
  const float* x  = (const float*)d_in[0];
  const float* Wg = (const float*)d_in[1];
  const float* bg = (const float*)d_in[2];
  const float* W1 = (const float*)d_in[3];
  const float* b1 = (const float*)d_in[4];
  const float* W2 = (const float*)d_in[5];
  const float* b2 = (const float*)d_in[6];
  float* out = (float*)d_out;

  char* ws = (char*)d_ws;
  size_t off = 0;
  auto alloc = [&](size_t bytes){ size_t r = off; off += (bytes + 255) & ~(size_t)255; return r; };

  unsigned short* W1t    = (unsigned short*)(ws + alloc((size_t)E_NUM * H_DIM * D_DIM * 2));
  unsigned short* W2t    = (unsigned short*)(ws + alloc((size_t)E_NUM * O_DIM * H_DIM * 2));
  unsigned short* xb     = (unsigned short*)(ws + alloc((size_t)NT_TOK * D_DIM * 2));
  unsigned short* hidden = (unsigned short*)(ws + alloc((size_t)PAIRS * H_DIM * 2));
  int*            pe     = (int*)           (ws + alloc(PAIRS * 4));
  float*          pw     = (float*)         (ws + alloc(PAIRS * 4));
  int*            row_pair = (int*)         (ws + alloc(PAIRS * 4));
  int*            cnt    = (int*)           (ws + alloc(64));
  int*            offs   = (int*)           (ws + alloc(64));
  int*            chist  = (int*)           (ws + alloc(32 * E_NUM * 4));
  int*            wi     = (int*)           (ws + alloc(WI_SLOTS * 4));
  int*            wi64   = (int*)           (ws + alloc(WI64_SLOTS * 4));

  // y (33.5 MB) aliases W1t (64 MB): W1t dead after gemm1, y written by gemm2 (stream order)
  float* yp = (float*)W1t;

  if (off > ws_size)
    fprintf(stderr, "kernel_launch: workspace too small: need %zu, have %zu\n", off, ws_size);

  hipMemsetAsync(chist, 0, 32 * E_NUM * 4, stream);          // hist accumulates via atomics
  gate_w1t_kernel<<<NT_TOK/4 + TW1_BLOCKS, 256, 0, stream>>>(x, Wg, bg, W1, xb, W1t, pe, pw, chist);
  scatter_kernel<<<1, 256, 0, stream>>>(pe, chist, cnt, offs, row_pair, wi, wi64);
  gemm1_w2t_kernel<<<G1_BLOCKS + TW2_BLOCKS, 256, 0, stream>>>(xb, W1t, W2, W2t, b1,
                                                               row_pair, cnt, offs, wi, hidden);
  gemm2_kernel<<<G2_BLOCKS, 256, 0, stream>>>(hidden, W2t, b2, row_pair, cnt, offs, wi64, yp);
  combine_kernel<<<NT_TOK, 256, 0, stream>>>(yp, pe, pw, out);
}

// Round 16
// 308.136 us; speedup vs baseline: 1.0608x; 1.0608x over previous
//
#include <hip/hip_runtime.h>
#include <hip/hip_bf16.h>
#include <cstdio>

// Problem constants (B=2, T=2048, D=1024, H=4096, O=1024, E=8, top-k=2)
#define NT_TOK 4096
#define D_DIM  1024
#define H_DIM  4096
#define O_DIM  1024
#define E_NUM  8
#define PAIRS  8192      // NT_TOK * 2
#define WI_SLOTS 72      // max m-tiles at BM=128: 64 + 7 rounding < 72
#define BK 64
#define G1_BLOCKS (32 * WI_SLOTS)   // 2304 gemm1 blocks
#define G2_BLOCKS (8 * WI_SLOTS)    // 576 gemm2 blocks; 576 % 8 == 0
#define TW1_BLOCKS (E_NUM * 1024)   // 8192 W1-transpose tiles
#define TW2_BLOCKS (E_NUM * 1024)   // 8192 W2-transpose tiles

typedef short bf16x8 __attribute__((ext_vector_type(8)));
typedef float f32x4  __attribute__((ext_vector_type(4)));

// round-to-nearest-even fp32 -> bf16 bits
__device__ __forceinline__ unsigned short bfr(float f){
  unsigned u = __float_as_uint(f);
  unsigned r = (u + 0x7FFFu + ((u >> 16) & 1u)) >> 16;
  return (unsigned short)r;
}

// async global->LDS, 16B per lane; lds dest is wave-uniform base (HW adds lane*16)
__device__ __forceinline__ void gload_lds16(const void* g, void* l){
  __builtin_amdgcn_global_load_lds((const __attribute__((address_space(1))) unsigned int*)g,
                                   (__attribute__((address_space(3))) unsigned int*)l,
                                   16, 0, 0);
}

// ---------------- 64x64 cast+transpose tile body ([R][C] f32 -> [C][R] bf16)
__device__ __forceinline__ void transpose_tile(const float* __restrict__ in,
                                               unsigned short* __restrict__ out,
                                               int R, int C, int bx, int by, int bz,
                                               char* smem){
  float (*t)[65] = (float(*)[65])smem;
  long long base = (long long)bz * R * C;
  int c0 = bx * 64, r0 = by * 64;
  int tid = threadIdx.x;
  int rr = tid >> 4;           // 0..15
  int cc = (tid & 15) * 4;     // 0,4,...,60
  #pragma unroll
  for (int i = 0; i < 4; i++){
    int r = rr + i * 16;
    float4 v = *(const float4*)&in[base + (long long)(r0 + r) * C + c0 + cc];
    t[r][cc] = v.x; t[r][cc+1] = v.y; t[r][cc+2] = v.z; t[r][cc+3] = v.w;
  }
  __syncthreads();
  #pragma unroll
  for (int i = 0; i < 4; i++){
    int oc = rr + i * 16;      // output row (= input col)
    unsigned int lo = (unsigned int)bfr(t[cc][oc])   | ((unsigned int)bfr(t[cc+1][oc]) << 16);
    unsigned int hi = (unsigned int)bfr(t[cc+2][oc]) | ((unsigned int)bfr(t[cc+3][oc]) << 16);
    *(uint2*)&out[base + (long long)(c0 + oc) * R + r0 + cc] = make_uint2(lo, hi);
  }
}

// ================== K1: gating (top-2) + fused hist + x->bf16 cast  ∥  W1 transpose
__global__ __launch_bounds__(256) void gate_w1t_kernel(const float* __restrict__ x,
                                                       const float* __restrict__ Wg,
                                                       const float* __restrict__ bg,
                                                       const float* __restrict__ W1,
                                                       unsigned short* __restrict__ xb,
                                                       unsigned short* __restrict__ W1t,
                                                       int*   __restrict__ pe,
                                                       float* __restrict__ pw,
                                                       int*   __restrict__ chist){
  __shared__ __align__(16) char smem[16640];
  int bid = blockIdx.x;
  if (bid >= NT_TOK/4){
    // W1 [D][H] -> W1t [H][D] per expert; bx over H/64 (64), by over D/64 (16)
    int tb = bid - NT_TOK/4;
    int e = tb >> 10, t = tb & 1023;
    transpose_tile(W1, W1t, D_DIM, H_DIM, t & 63, t >> 6, e, smem);
    return;
  }
  int wid = threadIdx.x >> 6, lane = threadIdx.x & 63;
  int t = bid * 4 + wid;
  const float* xr = x + (long long)t * D_DIM;
  unsigned short* xo = xb + (long long)t * D_DIM;
  float acc[E_NUM];
  #pragma unroll
  for (int e = 0; e < E_NUM; e++) acc[e] = 0.f;
  for (int d = lane; d < D_DIM; d += 64){
    float xv = xr[d];
    xo[d] = bfr(xv);                          // fused bf16 cast
    const float* wr = Wg + d * E_NUM;
    #pragma unroll
    for (int e = 0; e < E_NUM; e++) acc[e] += xv * wr[e];
  }
  #pragma unroll
  for (int off = 32; off; off >>= 1)
    #pragma unroll
    for (int e = 0; e < E_NUM; e++) acc[e] += __shfl_xor(acc[e], off);
  if (lane == 0){
    float l[E_NUM];
    float m = -1e30f;
    #pragma unroll
    for (int e = 0; e < E_NUM; e++){ l[e] = acc[e] + bg[e]; m = fmaxf(m, l[e]); }
    float ex[E_NUM];
    #pragma unroll
    for (int e = 0; e < E_NUM; e++) ex[e] = expf(l[e] - m);
    int e0 = 0;
    #pragma unroll
    for (int e = 1; e < E_NUM; e++) if (ex[e] > ex[e0]) e0 = e;      // first max
    int e1 = -1;
    for (int e = 0; e < E_NUM; e++){ if (e == e0) continue; if (e1 < 0 || ex[e] > ex[e1]) e1 = e; }
    float s = ex[e0] + ex[e1];
    pe[2*t]   = e0;  pw[2*t]   = ex[e0] / s;
    pe[2*t+1] = e1;  pw[2*t+1] = ex[e1] / s;
    int chunk = (2*t) >> 8;                   // both pair slots of t are in the same 256-chunk
    atomicAdd(&chist[chunk * E_NUM + e0], 1);
    atomicAdd(&chist[chunk * E_NUM + e1], 1);
  }
}

// --------------------------------- scan + deterministic scatter + work-item table
__global__ __launch_bounds__(256) void scatter_kernel(const int* __restrict__ pe,
                                                      const int* __restrict__ chunk_hist,
                                                      int* __restrict__ cnt,
                                                      int* __restrict__ offs,
                                                      int* __restrict__ row_pair,
                                                      int* __restrict__ wi){
  __shared__ int hist[32][E_NUM];
  __shared__ int pref[32][E_NUM];
  __shared__ int total[E_NUM];
  __shared__ int off_s[E_NUM + 1];
  __shared__ unsigned char ex[PAIRS];
  int tid = threadIdx.x;
  for (int i = tid; i < PAIRS; i += 256) ex[i] = (unsigned char)pe[i];
  { int c = tid >> 3, e = tid & 7; hist[c][e] = chunk_hist[tid]; }
  __syncthreads();
  if (tid < E_NUM){
    int s = 0;
    for (int c = 0; c < 32; c++){ pref[c][tid] = s; s += hist[c][tid]; }
    total[tid] = s;
  }
  __syncthreads();
  if (tid == 0){
    int s = 0;
    for (int e = 0; e < E_NUM; e++){ off_s[e] = s; s += total[e]; }
    off_s[E_NUM] = s;
    int idx = 0;
    for (int e = 0; e < E_NUM; e++){
      int mts = (total[e] + 127) >> 7;
      for (int m = 0; m < mts; m++) wi[idx++] = (e << 8) | m;
    }
    for (; idx < WI_SLOTS; idx++) wi[idx] = -1;
  }
  __syncthreads();
  if (tid < E_NUM){ cnt[tid] = total[tid]; offs[tid] = off_s[tid]; }
  int c = tid >> 3, e = tid & 7;
  int base = off_s[e] + pref[c][e];
  int local = 0;
  for (int i = 0; i < 256; i++){
    int p = c * 256 + i;
    if (ex[p] == (unsigned char)e){
      row_pair[base + local] = p;
      local++;
    }
  }
}

// ================== K3: grouped GEMM1 (m97 structure, NATURAL order)  ∥  W2 transpose
// hidden[pos][h] = relu( x[token(pos)] . W1[e][:, h] + b1[e][h] ), bf16 out
// Natural order measured best for gemm1 (R7/R11=137us vs chunked R9=146us).
__global__ __launch_bounds__(256, 3) void gemm1_w2t_kernel(const unsigned short* __restrict__ xb,
                                                           const unsigned short* __restrict__ W1t,
                                                           const float* __restrict__ W2,
                                                           unsigned short* __restrict__ W2t,
                                                           const float* __restrict__ b1,
                                                           const int* __restrict__ row_pair,
                                                           const int* __restrict__ cnt,
                                                           const int* __restrict__ offs,
                                                           const int* __restrict__ wi,
                                                           unsigned short* __restrict__ hidden){
  __shared__ __align__(16) char smem[32768];
  int bid = blockIdx.x;
  if (bid >= G1_BLOCKS){
    // W2 [H][O] -> W2t [O][H] per expert; bx over O/64 (16), by over H/64 (64)
    int tb = bid - G1_BLOCKS;
    int e = tb >> 10, t = tb & 1023;
    transpose_tile(W2, W2t, H_DIM, O_DIM, t & 15, t >> 4, e, smem);
    return;
  }
  int nt = bid & 31, slot = bid >> 5;
  int w = wi[slot];
  if (w < 0) return;
  int e = w >> 8, mt = w & 255;
  int count = cnt[e];
  int m0 = mt * 128;
  int seg = offs[e];
  int valid = count - m0;
  int n0 = nt * 128;

  unsigned short* As = (unsigned short*)smem;            // 16 KB
  unsigned short* Bs = (unsigned short*)(smem + 16384);  // 16 KB

  int tid = threadIdx.x;
  int wv = tid >> 6, lane = tid & 63;
  int wr = wv >> 1, wc = wv & 1;              // wave tile: rows wr*64..+63, cols wc*64..+63
  int lo = lane & 15, hi = lane >> 4;
  int l3 = lane >> 3;                         // 0..7 (= staged row & 7)
  int srcel = ((lane & 7) ^ l3) << 3;         // inverse-swizzled source column (elements)

  const unsigned short* w1e = W1t + (long long)e * H_DIM * D_DIM;   // [H][D]

  const unsigned short* pa[4];
  const unsigned short* pb[4];
  #pragma unroll
  for (int h = 0; h < 4; h++){
    int r = h * 32 + wv * 8 + l3;
    int pos = seg + m0 + r; if (pos > PAIRS - 1) pos = PAIRS - 1;
    int token = row_pair[pos] >> 1;
    pa[h] = xb + (long long)token * D_DIM + srcel;
    pb[h] = w1e + (long long)(n0 + r) * D_DIM + srcel;
  }

  f32x4 acc[4][4] = {};
  for (int kt = 0; kt < D_DIM / BK; ++kt){
    #pragma unroll
    for (int h = 0; h < 4; h++){
      gload_lds16(pa[h], &As[(h*32 + wv*8) * BK]);  pa[h] += BK;
      gload_lds16(pb[h], &Bs[(h*32 + wv*8) * BK]);  pb[h] += BK;
    }
    __syncthreads();
    bf16x8 aq[4][2], bq[4][2];
    #pragma unroll
    for (int n = 0; n < 4; n++)
      #pragma unroll
      for (int ks = 0; ks < 2; ks++){
        int br = wc*64 + n*16 + lo;
        bq[n][ks] = *(const bf16x8*)&Bs[br*BK + ((ks*32 + hi*8) ^ ((br & 7) << 3))];
      }
    #pragma unroll
    for (int m = 0; m < 4; m++)
      #pragma unroll
      for (int ks = 0; ks < 2; ks++){
        int ar = wr*64 + m*16 + lo;
        aq[m][ks] = *(const bf16x8*)&As[ar*BK + ((ks*32 + hi*8) ^ ((ar & 7) << 3))];
      }
    #pragma unroll
    for (int m = 0; m < 4; m++)
      #pragma unroll
      for (int n = 0; n < 4; n++)
        #pragma unroll
        for (int ks = 0; ks < 2; ks++)
          acc[m][n] = __builtin_amdgcn_mfma_f32_16x16x32_bf16(aq[m][ks], bq[n][ks], acc[m][n], 0, 0, 0);
    __syncthreads();
  }

  const float* b1e = b1 + (long long)e * H_DIM;
  #pragma unroll
  for (int n = 0; n < 4; n++){
    int col = n0 + wc*64 + n*16 + lo;
    float bias = b1e[col];
    #pragma unroll
    for (int m = 0; m < 4; m++)
      #pragma unroll
      for (int j = 0; j < 4; j++){
        int rl = wr*64 + m*16 + hi*4 + j;
        if (rl < valid){
          float v = acc[m][n][j] + bias;
          v = v > 0.f ? v : 0.f;
          hidden[(long long)(seg + m0 + rl) * H_DIM + col] = bfr(v);
        }
      }
  }
}

// ============================================================== grouped GEMM2
// y[p][o] = hidden[pos] . W2[e][:,o] + b2[e][o]   (full K; XCD-chunked 1D grid)
__global__ __launch_bounds__(256, 3) void gemm2_kernel(const unsigned short* __restrict__ hidden,
                                                       const unsigned short* __restrict__ W2t,
                                                       const float* __restrict__ b2,
                                                       const int* __restrict__ row_pair,
                                                       const int* __restrict__ cnt,
                                                       const int* __restrict__ offs,
                                                       const int* __restrict__ wi,
                                                       float* __restrict__ y){
  // XCD-chunked bijection (576 % 8 == 0): consecutive blocks in a chunk share
  // the 1 MB hidden A-panel (8x reuse in XCD L2). Measured win in R9/R11.
  int bid = blockIdx.x;
  int fp = (bid & 7) * (G2_BLOCKS / 8) + (bid >> 3);
  int nt = fp & 7, slot = fp >> 3;
  int w = wi[slot];
  if (w < 0) return;
  int e = w >> 8, mt = w & 255;
  int count = cnt[e];
  int m0 = mt * 128;
  int seg = offs[e];
  int valid = count - m0;
  int n0 = nt * 128;

  __shared__ unsigned short As[128 * BK];
  __shared__ unsigned short Bs[128 * BK];

  int tid = threadIdx.x;
  int wv = tid >> 6, lane = tid & 63;
  int wr = wv >> 1, wc = wv & 1;
  int lo = lane & 15, hi = lane >> 4;
  int l3 = lane >> 3;
  int srcel = ((lane & 7) ^ l3) << 3;

  const unsigned short* w2e = W2t + (long long)e * O_DIM * H_DIM;   // [O][H]

  const unsigned short* pa[4];
  const unsigned short* pb[4];
  #pragma unroll
  for (int h = 0; h < 4; h++){
    int r = h * 32 + wv * 8 + l3;
    long long pos = seg + m0 + r; if (pos > PAIRS - 1) pos = PAIRS - 1;
    pa[h] = hidden + pos * H_DIM + srcel;
    pb[h] = w2e + (long long)(n0 + r) * H_DIM + srcel;
  }

  f32x4 acc[4][4] = {};
  for (int kt = 0; kt < H_DIM / BK; ++kt){
    #pragma unroll
    for (int h = 0; h < 4; h++){
      gload_lds16(pa[h], &As[(h*32 + wv*8) * BK]);  pa[h] += BK;
      gload_lds16(pb[h], &Bs[(h*32 + wv*8) * BK]);  pb[h] += BK;
    }
    __syncthreads();
    bf16x8 aq[4][2], bq[4][2];
    #pragma unroll
    for (int n = 0; n < 4; n++)
      #pragma unroll
      for (int ks = 0; ks < 2; ks++){
        int br = wc*64 + n*16 + lo;
        bq[n][ks] = *(const bf16x8*)&Bs[br*BK + ((ks*32 + hi*8) ^ ((br & 7) << 3))];
      }
    #pragma unroll
    for (int m = 0; m < 4; m++)
      #pragma unroll
      for (int ks = 0; ks < 2; ks++){
        int ar = wr*64 + m*16 + lo;
        aq[m][ks] = *(const bf16x8*)&As[ar*BK + ((ks*32 + hi*8) ^ ((ar & 7) << 3))];
      }
    #pragma unroll
    for (int m = 0; m < 4; m++)
      #pragma unroll
      for (int n = 0; n < 4; n++)
        #pragma unroll
        for (int ks = 0; ks < 2; ks++)
          acc[m][n] = __builtin_amdgcn_mfma_f32_16x16x32_bf16(aq[m][ks], bq[n][ks], acc[m][n], 0, 0, 0);
    __syncthreads();
  }

  const float* b2e = b2 + (long long)e * O_DIM;
  #pragma unroll
  for (int m = 0; m < 4; m++)
    #pragma unroll
    for (int j = 0; j < 4; j++){
      int rl = wr*64 + m*16 + hi*4 + j;
      if (rl < valid){
        int p = row_pair[seg + m0 + rl];
        float* yr = y + (long long)p * O_DIM;
        #pragma unroll
        for (int n = 0; n < 4; n++){
          int col = n0 + wc*64 + n*16 + lo;
          yr[col] = acc[m][n][j] + b2e[col];
        }
      }
    }
}

// ---------------------------------------------------------------- combine
__global__ __launch_bounds__(256) void combine_kernel(const float* __restrict__ y,
                                                      const int* __restrict__ pe,
                                                      const float* __restrict__ pw,
                                                      float* __restrict__ out){
  int t = blockIdx.x, tid = threadIdx.x;      // 256 threads * float4 = 1024 = O_DIM
  float w0 = pw[2*t], w1 = pw[2*t+1];
  float4 a = ((const float4*)(y + (long long)(2*t) * O_DIM))[tid];
  float4 b = ((const float4*)(y + (long long)(2*t+1) * O_DIM))[tid];
  float4 r;
  r.x = w0 * a.x + w1 * b.x;
  r.y = w0 * a.y + w1 * b.y;
  r.z = w0 * a.z + w1 * b.z;
  r.w = w0 * a.w + w1 * b.w;
  ((float4*)(out + (long long)t * O_DIM))[tid] = r;
}

// ---------------------------------------------------------------- host
extern "C" void kernel_launch(void* const* d_in, const int* in_sizes, int n_in,
                              void* d_out, int out_size, void* d_ws, size_t ws_size,
                              hipStream_t stream){
  const float* x  = (const float*)d_in[0];
  const float* Wg = (const float*)d_in[1];
  const float* bg = (const float*)d_in[2];
  const float* W1 = (const float*)d_in[3];
  const float* b1 = (const float*)d_in[4];
  const float* W2 = (const float*)d_in[5];
  const float* b2 = (const float*)d_in[6];
  float* out = (float*)d_out;

  char* ws = (char*)d_ws;
  size_t off = 0;
  auto alloc = [&](size_t bytes){ size_t r = off; off += (bytes + 255) & ~(size_t)255; return r; };

  unsigned short* W1t    = (unsigned short*)(ws + alloc((size_t)E_NUM * H_DIM * D_DIM * 2));
  unsigned short* W2t    = (unsigned short*)(ws + alloc((size_t)E_NUM * O_DIM * H_DIM * 2));
  unsigned short* xb     = (unsigned short*)(ws + alloc((size_t)NT_TOK * D_DIM * 2));
  unsigned short* hidden = (unsigned short*)(ws + alloc((size_t)PAIRS * H_DIM * 2));
  int*            pe     = (int*)           (ws + alloc(PAIRS * 4));
  float*          pw     = (float*)         (ws + alloc(PAIRS * 4));
  int*            row_pair = (int*)         (ws + alloc(PAIRS * 4));
  int*            cnt    = (int*)           (ws + alloc(64));
  int*            offs   = (int*)           (ws + alloc(64));
  int*            chist  = (int*)           (ws + alloc(32 * E_NUM * 4));
  int*            wi     = (int*)           (ws + alloc(WI_SLOTS * 4));

  // y (33.5 MB) aliases W1t (64 MB): W1t dead after gemm1, y written by gemm2 (stream order)
  float* yp = (float*)W1t;

  if (off > ws_size)
    fprintf(stderr, "kernel_launch: workspace too small: need %zu, have %zu\n", off, ws_size);

  hipMemsetAsync(chist, 0, 32 * E_NUM * 4, stream);          // hist accumulates via atomics
  gate_w1t_kernel<<<NT_TOK/4 + TW1_BLOCKS, 256, 0, stream>>>(x, Wg, bg, W1, xb, W1t, pe, pw, chist);
  scatter_kernel<<<1, 256, 0, stream>>>(pe, chist, cnt, offs, row_pair, wi);
  gemm1_w2t_kernel<<<G1_BLOCKS + TW2_BLOCKS, 256, 0, stream>>>(xb, W1t, W2, W2t, b1,
                                                               row_pair, cnt, offs, wi, hidden);
  gemm2_kernel<<<G2_BLOCKS, 256, 0, stream>>>(hidden, W2t, b2, row_pair, cnt, offs, wi, yp);
  combine_kernel<<<NT_TOK, 256, 0, stream>>>(yp, pe, pw, out);
}